// Round 3
// baseline (889.055 us; speedup 1.0000x reference)
//
#include <hip/hip_runtime.h>
#include <cstdint>
#include <cstddef>

#define NROWS 16384
#define KDIM  16384
#define EPSF  1e-7f
#define MINN  1e-15f
#define MAXN  1e6f
#define KSPLIT 8
#define BK    32
#define KRANGE (KDIM/KSPLIT)   /* 2048 */
#define NSTEP  (KRANGE/BK)     /* 64 */

typedef __attribute__((ext_vector_type(8))) short short8;
typedef __attribute__((ext_vector_type(4))) float f32x4;

__device__ __forceinline__ short f2bf(float f){
  union { float f; unsigned u; } c; c.f = f;
  unsigned u = c.u;
  unsigned r = (u + 0x7FFFu + ((u >> 16) & 1u)) >> 16;   // RNE
  return (short)r;
}

__device__ __forceinline__ float wredsum(float v){
  v += __shfl_xor(v, 1);
  v += __shfl_xor(v, 2);
  v += __shfl_xor(v, 4);
  v += __shfl_xor(v, 8);
  v += __shfl_xor(v, 16);
  v += __shfl_xor(v, 32);
  return v;
}

// ---- ub = logmap0(proj(expmap0(proj_tan0(b)))) for b1 (wave0) and b2 (wave1)
__global__ __launch_bounds__(128) void k_bias(const float* __restrict__ b1,
                                              const float* __restrict__ b2,
                                              float* __restrict__ ub){
  int w = threadIdx.x >> 6, l = threadIdx.x & 63;
  const float* b = w ? b2 : b1;
  float bv = b[l];
  float tb = l ? bv : 0.f;
  float s  = wredsum(tb*tb);
  float xn = fmaxf(sqrtf(s), MINN);
  float sc = sinhf(xn)/xn;
  float e  = sc*tb;
  float s2 = wredsum(e*e);
  float x0 = sqrtf(fmaxf(1.f+s2, EPSF));
  float yn = fmaxf(sqrtf(s2), MINN);
  float th = fmaxf(x0, 1.f+EPSF);
  float u  = l ? acoshf(th)*e/yn : 0.f;
  ub[w*64 + l] = u;
}

// ---- per-row linear + mobius bias chain -> g (tangent-space input to aggregation)
template<int MODE>
__global__ __launch_bounds__(256) void k_linear(const float* __restrict__ in,
                                                const float* __restrict__ W,
                                                const float* __restrict__ ub,
                                                float* __restrict__ g){
  __shared__ float Wt[64*65];
  int tid = threadIdx.x;
  for(int idx = tid; idx < 4096; idx += 256){
    int j = idx >> 6, k = idx & 63;
    Wt[k*65 + j] = W[idx];
  }
  __syncthreads();
  int lane = tid & 63;
  int row  = blockIdx.x*4 + (tid >> 6);
  float v = in[(size_t)row*64 + lane];
  float lx;
  if (MODE == 0){
    float t  = lane ? v : 0.f;
    float s  = wredsum(t*t);
    float tn = fmaxf(sqrtf(s), MINN);
    float sc = sinhf(tn)/tn;
    float e  = sc*t;
    float s2 = wredsum(e*e);
    float x0 = sqrtf(fmaxf(1.f+s2, EPSF));
    float yn = fmaxf(sqrtf(s2), MINN);
    float th = fmaxf(x0, 1.f+EPSF);
    lx = lane ? acoshf(th)*e/yn : 0.f;
  } else {
    float t  = lane ? v : 0.f;
    float s2 = wredsum(t*t);
    float x0 = __shfl(v, 0);
    float yn = fmaxf(sqrtf(s2), MINN);
    float th = fmaxf(x0, 1.f+EPSF);
    lx = lane ? acoshf(th)*t/yn : 0.f;
  }
  float mv = 0.f;
  #pragma unroll
  for(int k = 0; k < 64; k++){
    mv = fmaf(__shfl(lx, k), Wt[k*65 + lane], mv);
  }
  float u  = lane ? mv : 0.f;
  float s  = wredsum(u*u);
  float un = fmaxf(sqrtf(s), MINN);
  float sc = sinhf(un)/un;
  float e  = sc*u;
  float s2 = wredsum(e*e);
  float r0 = sqrtf(fmaxf(1.f+s2, EPSF));
  float ubt   = lane ? ub[lane] : 0.f;
  float yn    = fmaxf(sqrtf(s2), MINN);
  float yhat  = e/yn;
  float alpha = wredsum(yhat*ubt);
  float w     = ubt - alpha*(1.f - r0)*yhat;
  float ux    = wredsum(e*w);
  float v0    = ux / fmaxf(r0, EPSF);
  float md    = wredsum(w*w) - v0*v0;
  float normu = fminf(sqrtf(fmaxf(md, EPSF)), MAXN);
  float th2   = fmaxf(normu, MINN);
  float ch    = coshf(th2);
  float shq   = sinhf(th2)/th2;
  float ov    = ch*(lane ? e : r0) + shq*(lane ? w : v0);
  float ot    = lane ? ov : 0.f;
  float s3    = wredsum(ot*ot);
  float o0    = sqrtf(fmaxf(1.f+s3, EPSF));
  float yn2 = fmaxf(sqrtf(s3), MINN);
  float th3 = fmaxf(o0, 1.f+EPSF);
  float gv  = lane ? acoshf(th3)*ot/yn2 : 0.f;
  g[(size_t)row*64 + lane] = gv;
}

// ---- transpose + bf16 convert: g[N][64] f32 -> gT[64][N] bf16
__global__ __launch_bounds__(256) void k_tr(const float* __restrict__ g,
                                            short* __restrict__ gT){
  __shared__ float t[64][65];
  int tid = threadIdx.x;
  int b   = blockIdx.x;               // 64-row chunk
  int r   = tid >> 2;
  int c0  = (tid & 3)*16;
  const float* src = g + ((size_t)b*64 + r)*64 + c0;
  #pragma unroll
  for(int i = 0; i < 4; i++){
    float4 v = *(const float4*)(src + i*4);
    t[r][c0 + i*4 + 0] = v.x; t[r][c0 + i*4 + 1] = v.y;
    t[r][c0 + i*4 + 2] = v.z; t[r][c0 + i*4 + 3] = v.w;
  }
  __syncthreads();
  int n   = tid >> 2;
  int seg = tid & 3;                  // 16 k's
  short8 p0, p1;
  #pragma unroll
  for(int j = 0; j < 8; j++) p0[j] = f2bf(t[seg*16 + j][n]);
  #pragma unroll
  for(int j = 0; j < 8; j++) p1[j] = f2bf(t[seg*16 + 8 + j][n]);
  short* dst = gT + (size_t)n*KDIM + b*64 + seg*16;
  *(short8*)(dst)     = p0;
  *(short8*)(dst + 8) = p1;
}

// ---- LDS-free, barrier-free MFMA split-K matmul:
// pagg[ks] = adj[:, krange] @ g[krange, :]; rowsum partials if FIRST
template<bool FIRST>
__global__ __launch_bounds__(256) void k_matmul(const float* __restrict__ adj,
                                                const short* __restrict__ gT,
                                                float* __restrict__ pagg,
                                                float* __restrict__ prsum){
  int tid  = threadIdx.x;
  int lane = tid & 63, w = tid >> 6;
  int rb   = blockIdx.x;
  int ks   = blockIdx.y;
  int row0 = rb*64;
  size_t k0 = (size_t)ks * KRANGE;
  int r  = lane & 15;                 // A row within wave strip / B col within 16-group
  int kg = lane >> 4;                 // k-group of 8

  const float* aptr = adj + (size_t)(row0 + w*16 + r)*KDIM + k0 + (size_t)kg*8;
  const short* bptr = gT + (size_t)r*KDIM + k0 + (size_t)kg*8;

  f32x4 acc[4];
  #pragma unroll
  for(int i = 0; i < 4; i++) acc[i] = (f32x4){0.f,0.f,0.f,0.f};
  float rs = 0.f;

  // prologue: step 0 loads
  float4 a0 = *(const float4*)(aptr);
  float4 a1 = *(const float4*)(aptr + 4);
  short8 b0 = *(const short8*)(bptr);
  short8 b1 = *(const short8*)(bptr + (size_t)16*KDIM);
  short8 b2 = *(const short8*)(bptr + (size_t)32*KDIM);
  short8 b3 = *(const short8*)(bptr + (size_t)48*KDIM);

  for(int ch = 0; ch < NSTEP; ch++){
    // prefetch next step (consumed after this step's MFMAs; counted vmcnt, no barrier)
    float4 a0n, a1n; short8 b0n, b1n, b2n, b3n;
    if (ch + 1 < NSTEP){
      const float* ap = aptr + (size_t)(ch+1)*BK;
      a0n = *(const float4*)(ap);
      a1n = *(const float4*)(ap + 4);
      const short* bp = bptr + (size_t)(ch+1)*BK;
      b0n = *(const short8*)(bp);
      b1n = *(const short8*)(bp + (size_t)16*KDIM);
      b2n = *(const short8*)(bp + (size_t)32*KDIM);
      b3n = *(const short8*)(bp + (size_t)48*KDIM);
    }
    if (FIRST){
      rs += a0.x + a0.y + a0.z + a0.w + a1.x + a1.y + a1.z + a1.w;
    }
    short8 af;
    af[0] = f2bf(a0.x); af[1] = f2bf(a0.y); af[2] = f2bf(a0.z); af[3] = f2bf(a0.w);
    af[4] = f2bf(a1.x); af[5] = f2bf(a1.y); af[6] = f2bf(a1.z); af[7] = f2bf(a1.w);
    acc[0] = __builtin_amdgcn_mfma_f32_16x16x32_bf16(af, b0, acc[0], 0, 0, 0);
    acc[1] = __builtin_amdgcn_mfma_f32_16x16x32_bf16(af, b1, acc[1], 0, 0, 0);
    acc[2] = __builtin_amdgcn_mfma_f32_16x16x32_bf16(af, b2, acc[2], 0, 0, 0);
    acc[3] = __builtin_amdgcn_mfma_f32_16x16x32_bf16(af, b3, acc[3], 0, 0, 0);
    a0 = a0n; a1 = a1n;
    b0 = b0n; b1 = b1n; b2 = b2n; b3 = b3n;
  }

  if (FIRST){
    // reduce k-groups: lanes l, l^16, l^32, l^48 hold partials of row (l&15)
    rs += __shfl_xor(rs, 16);
    rs += __shfl_xor(rs, 32);
    if (lane < 16){
      prsum[(size_t)ks*NROWS + row0 + w*16 + lane] = rs;
    }
  }
  // C write: wave w owns rows [w*16, w*16+16); D: n = lane&15, m = (lane>>4)*4 + reg
  float* ob = pagg + ((size_t)ks*NROWS + row0 + w*16)*64;
  #pragma unroll
  for(int nb = 0; nb < 4; nb++){
    int n = nb*16 + (lane & 15);
    #pragma unroll
    for(int q = 0; q < 4; q++){
      int m = (lane >> 4)*4 + q;
      ob[(size_t)m*64 + n] = acc[nb][q];
    }
  }
}

// ---- fused: split-K reduce + (layer1: rinv compute/store) + postagg chain -> h
template<int LAYER>
__global__ __launch_bounds__(256) void k_post(const float* __restrict__ pagg,
                                              const float* __restrict__ prsum,
                                              float* __restrict__ rinv,
                                              float* __restrict__ h){
  int tid = threadIdx.x; int lane = tid & 63;
  int row = blockIdx.x*4 + (tid >> 6);
  float s = 0.f;
  #pragma unroll
  for(int ks = 0; ks < KSPLIT; ks++) s += pagg[(size_t)ks*NROWS*64 + (size_t)row*64 + lane];
  float ri;
  if (LAYER == 1){
    float rsum = 0.f;
    #pragma unroll
    for(int ks = 0; ks < KSPLIT; ks++) rsum += prsum[(size_t)ks*NROWS + row];
    ri = (rsum != 0.f) ? 1.f/rsum : 0.f;
    if (lane == 0) rinv[row] = ri;
  } else {
    ri = rinv[row];
  }
  float a  = s * ri;
  float at = lane ? a : 0.f;
  float ss = wredsum(at*at);
  float un = fmaxf(sqrtf(ss), MINN);
  float sc = sinhf(un)/un;
  float e  = sc*at;
  float s2 = wredsum(e*e);
  float x0 = sqrtf(fmaxf(1.f+s2, EPSF));
  float yn = fmaxf(sqrtf(s2), MINN);
  float th = fmaxf(x0, 1.f+EPSF);
  float lt = lane ? acoshf(th)*e/yn : 0.f;
  float rl = fmaxf(lt, 0.f);
  float s3 = wredsum(rl*rl);
  float rn = fmaxf(sqrtf(s3), MINN);
  float sc2= sinhf(rn)/rn;
  float e2 = sc2*rl;
  float s4 = wredsum(e2*e2);
  float h0 = sqrtf(fmaxf(1.f+s4, EPSF));
  h[(size_t)row*64 + lane] = lane ? e2 : h0;
}

extern "C" void kernel_launch(void* const* d_in, const int* in_sizes, int n_in,
                              void* d_out, int out_size, void* d_ws, size_t ws_size,
                              hipStream_t stream){
  const float* x   = (const float*)d_in[0];
  const float* adj = (const float*)d_in[1];
  const float* W1  = (const float*)d_in[2];
  const float* b1  = (const float*)d_in[3];
  const float* W2  = (const float*)d_in[4];
  const float* b2  = (const float*)d_in[5];
  float* out = (float*)d_out;
  float* h1  = out;
  float* h2  = out + (size_t)NROWS*64;

  float* wsf   = (float*)d_ws;
  float* gbuf  = wsf;                              // N*64 f32
  float* pagg  = gbuf  + (size_t)NROWS*64;         // KSPLIT*N*64 f32
  float* prsum = pagg  + (size_t)KSPLIT*NROWS*64;  // KSPLIT*N
  float* rinv  = prsum + (size_t)KSPLIT*NROWS;     // N
  float* ubs   = rinv  + NROWS;                    // 128
  short* gT    = (short*)(ubs + 128);              // 64*N bf16

  dim3 gm(NROWS/64, KSPLIT);

  k_bias<<<1, 128, 0, stream>>>(b1, b2, ubs);
  // layer 1
  k_linear<0><<<NROWS/4, 256, 0, stream>>>(x, W1, ubs, gbuf);
  k_tr<<<NROWS/64, 256, 0, stream>>>(gbuf, gT);
  k_matmul<true><<<gm, 256, 0, stream>>>(adj, gT, pagg, prsum);
  k_post<1><<<NROWS/4, 256, 0, stream>>>(pagg, prsum, rinv, h1);
  // layer 2
  k_linear<1><<<NROWS/4, 256, 0, stream>>>(h1, W2, ubs + 64, gbuf);
  k_tr<<<NROWS/64, 256, 0, stream>>>(gbuf, gT);
  k_matmul<false><<<gm, 256, 0, stream>>>(adj, gT, pagg, prsum);
  k_post<2><<<NROWS/4, 256, 0, stream>>>(pagg, prsum, rinv, h2);
}

// Round 4
// 658.818 us; speedup vs baseline: 1.3495x; 1.3495x over previous
//
#include <hip/hip_runtime.h>
#include <cstdint>
#include <cstddef>

#define NROWS 16384
#define KDIM  16384
#define EPSF  1e-7f
#define MINN  1e-15f
#define MAXN  1e6f
#define KSPLIT 8
#define BK    32
#define KRANGE (KDIM/KSPLIT)   /* 2048 */
#define NSTEP  (KRANGE/BK)     /* 64 */
#define PGS    1040            /* LDS page stride: 64*16B + 16B pad */

typedef __attribute__((ext_vector_type(8))) short short8;
typedef __attribute__((ext_vector_type(4))) float f32x4;
typedef __attribute__((ext_vector_type(4))) unsigned short u16x4;

__device__ __forceinline__ short f2bf(float f){
  union { float f; unsigned u; } c; c.f = f;
  unsigned u = c.u;
  unsigned r = (u + 0x7FFFu + ((u >> 16) & 1u)) >> 16;   // RNE
  return (short)r;
}

__device__ __forceinline__ float wredsum(float v){
  v += __shfl_xor(v, 1);
  v += __shfl_xor(v, 2);
  v += __shfl_xor(v, 4);
  v += __shfl_xor(v, 8);
  v += __shfl_xor(v, 16);
  v += __shfl_xor(v, 32);
  return v;
}

// ---- ub = logmap0(proj(expmap0(proj_tan0(b)))) for b1 (wave0) and b2 (wave1)
__global__ __launch_bounds__(128) void k_bias(const float* __restrict__ b1,
                                              const float* __restrict__ b2,
                                              float* __restrict__ ub){
  int w = threadIdx.x >> 6, l = threadIdx.x & 63;
  const float* b = w ? b2 : b1;
  float bv = b[l];
  float tb = l ? bv : 0.f;
  float s  = wredsum(tb*tb);
  float xn = fmaxf(sqrtf(s), MINN);
  float sc = sinhf(xn)/xn;
  float e  = sc*tb;
  float s2 = wredsum(e*e);
  float x0 = sqrtf(fmaxf(1.f+s2, EPSF));
  float yn = fmaxf(sqrtf(s2), MINN);
  float th = fmaxf(x0, 1.f+EPSF);
  float u  = l ? acoshf(th)*e/yn : 0.f;
  ub[w*64 + l] = u;
}

// ---- per-row linear + mobius bias chain -> g (tangent-space input to aggregation)
template<int MODE>
__global__ __launch_bounds__(256) void k_linear(const float* __restrict__ in,
                                                const float* __restrict__ W,
                                                const float* __restrict__ ub,
                                                float* __restrict__ g){
  __shared__ float Wt[64*65];
  int tid = threadIdx.x;
  for(int idx = tid; idx < 4096; idx += 256){
    int j = idx >> 6, k = idx & 63;
    Wt[k*65 + j] = W[idx];
  }
  __syncthreads();
  int lane = tid & 63;
  int row  = blockIdx.x*4 + (tid >> 6);
  float v = in[(size_t)row*64 + lane];
  float lx;
  if (MODE == 0){
    float t  = lane ? v : 0.f;
    float s  = wredsum(t*t);
    float tn = fmaxf(sqrtf(s), MINN);
    float sc = sinhf(tn)/tn;
    float e  = sc*t;
    float s2 = wredsum(e*e);
    float x0 = sqrtf(fmaxf(1.f+s2, EPSF));
    float yn = fmaxf(sqrtf(s2), MINN);
    float th = fmaxf(x0, 1.f+EPSF);
    lx = lane ? acoshf(th)*e/yn : 0.f;
  } else {
    float t  = lane ? v : 0.f;
    float s2 = wredsum(t*t);
    float x0 = __shfl(v, 0);
    float yn = fmaxf(sqrtf(s2), MINN);
    float th = fmaxf(x0, 1.f+EPSF);
    lx = lane ? acoshf(th)*t/yn : 0.f;
  }
  float mv = 0.f;
  #pragma unroll
  for(int k = 0; k < 64; k++){
    mv = fmaf(__shfl(lx, k), Wt[k*65 + lane], mv);
  }
  float u  = lane ? mv : 0.f;
  float s  = wredsum(u*u);
  float un = fmaxf(sqrtf(s), MINN);
  float sc = sinhf(un)/un;
  float e  = sc*u;
  float s2 = wredsum(e*e);
  float r0 = sqrtf(fmaxf(1.f+s2, EPSF));
  float ubt   = lane ? ub[lane] : 0.f;
  float yn    = fmaxf(sqrtf(s2), MINN);
  float yhat  = e/yn;
  float alpha = wredsum(yhat*ubt);
  float w     = ubt - alpha*(1.f - r0)*yhat;
  float ux    = wredsum(e*w);
  float v0    = ux / fmaxf(r0, EPSF);
  float md    = wredsum(w*w) - v0*v0;
  float normu = fminf(sqrtf(fmaxf(md, EPSF)), MAXN);
  float th2   = fmaxf(normu, MINN);
  float ch    = coshf(th2);
  float shq   = sinhf(th2)/th2;
  float ov    = ch*(lane ? e : r0) + shq*(lane ? w : v0);
  float ot    = lane ? ov : 0.f;
  float s3    = wredsum(ot*ot);
  float o0    = sqrtf(fmaxf(1.f+s3, EPSF));
  float yn2 = fmaxf(sqrtf(s3), MINN);
  float th3 = fmaxf(o0, 1.f+EPSF);
  float gv  = lane ? acoshf(th3)*ot/yn2 : 0.f;
  g[(size_t)row*64 + lane] = gv;
}

// ---- transpose + bf16 convert: g[N][64] f32 -> gT[64][N] bf16
__global__ __launch_bounds__(256) void k_tr(const float* __restrict__ g,
                                            short* __restrict__ gT){
  __shared__ float t[64][65];
  int tid = threadIdx.x;
  int b   = blockIdx.x;               // 64-row chunk
  int r   = tid >> 2;
  int c0  = (tid & 3)*16;
  const float* src = g + ((size_t)b*64 + r)*64 + c0;
  #pragma unroll
  for(int i = 0; i < 4; i++){
    float4 v = *(const float4*)(src + i*4);
    t[r][c0 + i*4 + 0] = v.x; t[r][c0 + i*4 + 1] = v.y;
    t[r][c0 + i*4 + 2] = v.z; t[r][c0 + i*4 + 3] = v.w;
  }
  __syncthreads();
  int n   = tid >> 2;
  int seg = tid & 3;                  // 16 k's
  short8 p0, p1;
  #pragma unroll
  for(int j = 0; j < 8; j++) p0[j] = f2bf(t[seg*16 + j][n]);
  #pragma unroll
  for(int j = 0; j < 8; j++) p1[j] = f2bf(t[seg*16 + 8 + j][n]);
  short* dst = gT + (size_t)n*KDIM + b*64 + seg*16;
  *(short8*)(dst)     = p0;
  *(short8*)(dst + 8) = p1;
}

// ---- MFMA split-K matmul (LDS-staged, ks-in-low-grid-bits for XCD L2 affinity):
// pagg[ks] = adj[:, krange] @ g[krange, :]; rowsum partials if FIRST
template<bool FIRST>
__global__ __launch_bounds__(256) void k_matmul(const float* __restrict__ adj,
                                                const short* __restrict__ gT,
                                                float* __restrict__ pagg,
                                                float* __restrict__ prsum){
  __shared__ __align__(16) char As[4*PGS];
  __shared__ __align__(16) char Bs[4*PGS];
  int tid  = threadIdx.x;
  int ks   = blockIdx.x;               // low bits of linear block id -> XCD = ks
  int rb   = blockIdx.y;
  int row0 = rb*64;
  size_t k0 = (size_t)ks * KRANGE;
  int lane = tid & 63, w = tid >> 6;

  // A staging: thread covers rows r0, r0+32 at k-quad kq (full 128B/row per 8 lanes)
  int r0 = tid >> 3;
  int kq = tid & 7;
  const float* arow0 = adj + (size_t)(row0 + r0)*KDIM + k0 + kq*4;
  const float* arow1 = arow0 + (size_t)32*KDIM;
  char* Awr = As + (kq >> 1)*PGS + r0*16 + (kq & 1)*8;

  // B staging: thread (kgB, nB) reads gT[nB][k..k+8] contiguous bf16
  int nB  = tid & 63;
  int kgB = tid >> 6;
  const short* bsrc = gT + (size_t)nB*KDIM + k0 + kgB*8;
  char* Bwr = Bs + kgB*PGS + nB*16;

  // fragment read pointers
  const char* Ard  = As + (lane >> 4)*PGS + (w*16 + (lane & 15))*16;
  const char* Brd0 = Bs + (lane >> 4)*PGS + (lane & 15)*16;

  f32x4 acc[4];
  #pragma unroll
  for(int i = 0; i < 4; i++) acc[i] = (f32x4){0.f,0.f,0.f,0.f};
  float rsA = 0.f, rsB = 0.f;

  // prologue loads (step 0)
  float4 a0 = *(const float4*)(arow0);
  float4 a1 = *(const float4*)(arow1);
  short8 bv = *(const short8*)(bsrc);

  for(int ch = 0; ch < NSTEP; ch++){
    if (FIRST){
      rsA += a0.x + a0.y + a0.z + a0.w;
      rsB += a1.x + a1.y + a1.z + a1.w;
    }
    __syncthreads();                       // previous step's frag reads done
    u16x4 ap0 = { (unsigned short)f2bf(a0.x), (unsigned short)f2bf(a0.y),
                  (unsigned short)f2bf(a0.z), (unsigned short)f2bf(a0.w) };
    u16x4 ap1 = { (unsigned short)f2bf(a1.x), (unsigned short)f2bf(a1.y),
                  (unsigned short)f2bf(a1.z), (unsigned short)f2bf(a1.w) };
    *(u16x4*)(Awr)       = ap0;            // row r0
    *(u16x4*)(Awr + 512) = ap1;            // row r0+32
    *(short8*)(Bwr)      = bv;
    __syncthreads();                       // staging visible
    short8 af  = *(const short8*)(Ard);
    short8 bf0 = *(const short8*)(Brd0);
    short8 bf1 = *(const short8*)(Brd0 + 256);
    short8 bf2 = *(const short8*)(Brd0 + 512);
    short8 bf3 = *(const short8*)(Brd0 + 768);
    // prefetch next step during MFMA phase (drains at next barrier)
    if (ch + 1 < NSTEP){
      const float* ap = arow0 + (size_t)(ch+1)*BK;
      a0 = *(const float4*)(ap);
      a1 = *(const float4*)(ap + (size_t)32*KDIM);
      bv = *(const short8*)(bsrc + (size_t)(ch+1)*BK);
    }
    acc[0] = __builtin_amdgcn_mfma_f32_16x16x32_bf16(af, bf0, acc[0], 0, 0, 0);
    acc[1] = __builtin_amdgcn_mfma_f32_16x16x32_bf16(af, bf1, acc[1], 0, 0, 0);
    acc[2] = __builtin_amdgcn_mfma_f32_16x16x32_bf16(af, bf2, acc[2], 0, 0, 0);
    acc[3] = __builtin_amdgcn_mfma_f32_16x16x32_bf16(af, bf3, acc[3], 0, 0, 0);
  }

  if (FIRST){
    rsA += __shfl_xor(rsA, 1); rsA += __shfl_xor(rsA, 2); rsA += __shfl_xor(rsA, 4);
    rsB += __shfl_xor(rsB, 1); rsB += __shfl_xor(rsB, 2); rsB += __shfl_xor(rsB, 4);
    if (kq == 0){
      prsum[(size_t)ks*NROWS + row0 + r0]      = rsA;
      prsum[(size_t)ks*NROWS + row0 + r0 + 32] = rsB;
    }
  }
  // C write: wave w owns rows [w*16, w*16+16); D: n = lane&15, m = (lane>>4)*4 + reg
  float* ob = pagg + ((size_t)ks*NROWS + row0 + w*16)*64;
  #pragma unroll
  for(int nb = 0; nb < 4; nb++){
    int n = nb*16 + (lane & 15);
    #pragma unroll
    for(int q = 0; q < 4; q++){
      int m = (lane >> 4)*4 + q;
      ob[(size_t)m*64 + n] = acc[nb][q];
    }
  }
}

// ---- fused: split-K reduce + (layer1: rinv compute/store) + postagg chain -> h
template<int LAYER>
__global__ __launch_bounds__(256) void k_post(const float* __restrict__ pagg,
                                              const float* __restrict__ prsum,
                                              float* __restrict__ rinv,
                                              float* __restrict__ h){
  int tid = threadIdx.x; int lane = tid & 63;
  int row = blockIdx.x*4 + (tid >> 6);
  float s = 0.f;
  #pragma unroll
  for(int ks = 0; ks < KSPLIT; ks++) s += pagg[(size_t)ks*NROWS*64 + (size_t)row*64 + lane];
  float ri;
  if (LAYER == 1){
    float rsum = 0.f;
    #pragma unroll
    for(int ks = 0; ks < KSPLIT; ks++) rsum += prsum[(size_t)ks*NROWS + row];
    ri = (rsum != 0.f) ? 1.f/rsum : 0.f;
    if (lane == 0) rinv[row] = ri;
  } else {
    ri = rinv[row];
  }
  float a  = s * ri;
  float at = lane ? a : 0.f;
  float ss = wredsum(at*at);
  float un = fmaxf(sqrtf(ss), MINN);
  float sc = sinhf(un)/un;
  float e  = sc*at;
  float s2 = wredsum(e*e);
  float x0 = sqrtf(fmaxf(1.f+s2, EPSF));
  float yn = fmaxf(sqrtf(s2), MINN);
  float th = fmaxf(x0, 1.f+EPSF);
  float lt = lane ? acoshf(th)*e/yn : 0.f;
  float rl = fmaxf(lt, 0.f);
  float s3 = wredsum(rl*rl);
  float rn = fmaxf(sqrtf(s3), MINN);
  float sc2= sinhf(rn)/rn;
  float e2 = sc2*rl;
  float s4 = wredsum(e2*e2);
  float h0 = sqrtf(fmaxf(1.f+s4, EPSF));
  h[(size_t)row*64 + lane] = lane ? e2 : h0;
}

extern "C" void kernel_launch(void* const* d_in, const int* in_sizes, int n_in,
                              void* d_out, int out_size, void* d_ws, size_t ws_size,
                              hipStream_t stream){
  const float* x   = (const float*)d_in[0];
  const float* adj = (const float*)d_in[1];
  const float* W1  = (const float*)d_in[2];
  const float* b1  = (const float*)d_in[3];
  const float* W2  = (const float*)d_in[4];
  const float* b2  = (const float*)d_in[5];
  float* out = (float*)d_out;
  float* h1  = out;
  float* h2  = out + (size_t)NROWS*64;

  float* wsf   = (float*)d_ws;
  float* gbuf  = wsf;                              // N*64 f32
  float* pagg  = gbuf  + (size_t)NROWS*64;         // KSPLIT*N*64 f32
  float* prsum = pagg  + (size_t)KSPLIT*NROWS*64;  // KSPLIT*N
  float* rinv  = prsum + (size_t)KSPLIT*NROWS;     // N
  float* ubs   = rinv  + NROWS;                    // 128
  short* gT    = (short*)(ubs + 128);              // 64*N bf16

  dim3 gm(KSPLIT, NROWS/64);                       // ks in LOW bits -> XCD = ks

  k_bias<<<1, 128, 0, stream>>>(b1, b2, ubs);
  // layer 1
  k_linear<0><<<NROWS/4, 256, 0, stream>>>(x, W1, ubs, gbuf);
  k_tr<<<NROWS/64, 256, 0, stream>>>(gbuf, gT);
  k_matmul<true><<<gm, 256, 0, stream>>>(adj, gT, pagg, prsum);
  k_post<1><<<NROWS/4, 256, 0, stream>>>(pagg, prsum, rinv, h1);
  // layer 2
  k_linear<1><<<NROWS/4, 256, 0, stream>>>(h1, W2, ubs + 64, gbuf);
  k_tr<<<NROWS/64, 256, 0, stream>>>(gbuf, gT);
  k_matmul<false><<<gm, 256, 0, stream>>>(adj, gT, pagg, prsum);
  k_post<2><<<NROWS/4, 256, 0, stream>>>(pagg, prsum, rinv, h2);
}

// Round 5
// 606.370 us; speedup vs baseline: 1.4662x; 1.0865x over previous
//
#include <hip/hip_runtime.h>
#include <cstdint>
#include <cstddef>

#define NROWS 16384
#define KDIM  16384
#define EPSF  1e-7f
#define MINN  1e-15f
#define MAXN  1e6f
#define BM    32               /* rows per block */
#define BK2   64               /* K per step */
#define NSTEP2 (KDIM/BK2)      /* 256 */
#define APG   528              /* A page stride: 32*16B + 16B pad */
#define BPG   1040             /* B page stride: 64*16B + 16B pad */
#define ABUF  (8*APG)          /* 4224 */
#define BBUF  (8*BPG)          /* 8320 */

typedef __attribute__((ext_vector_type(8))) short short8;
typedef __attribute__((ext_vector_type(4))) float f32x4;
typedef __attribute__((ext_vector_type(4))) unsigned short u16x4;

__device__ __forceinline__ unsigned short f2bf(float f){
  union { float f; unsigned u; } c; c.f = f;
  unsigned u = c.u;
  unsigned r = (u + 0x7FFFu + ((u >> 16) & 1u)) >> 16;   // RNE
  return (unsigned short)r;
}

__device__ __forceinline__ float wredsum(float v){
  v += __shfl_xor(v, 1);
  v += __shfl_xor(v, 2);
  v += __shfl_xor(v, 4);
  v += __shfl_xor(v, 8);
  v += __shfl_xor(v, 16);
  v += __shfl_xor(v, 32);
  return v;
}

// ---- ub = logmap0(proj(expmap0(proj_tan0(b)))) for b1 (wave0) and b2 (wave1)
__global__ __launch_bounds__(128) void k_bias(const float* __restrict__ b1,
                                              const float* __restrict__ b2,
                                              float* __restrict__ ub){
  int w = threadIdx.x >> 6, l = threadIdx.x & 63;
  const float* b = w ? b2 : b1;
  float bv = b[l];
  float tb = l ? bv : 0.f;
  float s  = wredsum(tb*tb);
  float xn = fmaxf(sqrtf(s), MINN);
  float sc = sinhf(xn)/xn;
  float e  = sc*tb;
  float s2 = wredsum(e*e);
  float x0 = sqrtf(fmaxf(1.f+s2, EPSF));
  float yn = fmaxf(sqrtf(s2), MINN);
  float th = fmaxf(x0, 1.f+EPSF);
  float u  = l ? acoshf(th)*e/yn : 0.f;
  ub[w*64 + l] = u;
}

// ---- per-row linear + mobius bias chain -> g
template<int MODE>
__global__ __launch_bounds__(256) void k_linear(const float* __restrict__ in,
                                                const float* __restrict__ W,
                                                const float* __restrict__ ub,
                                                float* __restrict__ g){
  __shared__ float Wt[64*65];
  int tid = threadIdx.x;
  for(int idx = tid; idx < 4096; idx += 256){
    int j = idx >> 6, k = idx & 63;
    Wt[k*65 + j] = W[idx];
  }
  __syncthreads();
  int lane = tid & 63;
  int row  = blockIdx.x*4 + (tid >> 6);
  float v = in[(size_t)row*64 + lane];
  float lx;
  if (MODE == 0){
    float t  = lane ? v : 0.f;
    float s  = wredsum(t*t);
    float tn = fmaxf(sqrtf(s), MINN);
    float sc = sinhf(tn)/tn;
    float e  = sc*t;
    float s2 = wredsum(e*e);
    float x0 = sqrtf(fmaxf(1.f+s2, EPSF));
    float yn = fmaxf(sqrtf(s2), MINN);
    float th = fmaxf(x0, 1.f+EPSF);
    lx = lane ? acoshf(th)*e/yn : 0.f;
  } else {
    float t  = lane ? v : 0.f;
    float s2 = wredsum(t*t);
    float x0 = __shfl(v, 0);
    float yn = fmaxf(sqrtf(s2), MINN);
    float th = fmaxf(x0, 1.f+EPSF);
    lx = lane ? acoshf(th)*t/yn : 0.f;
  }
  float mv = 0.f;
  #pragma unroll
  for(int k = 0; k < 64; k++){
    mv = fmaf(__shfl(lx, k), Wt[k*65 + lane], mv);
  }
  float u  = lane ? mv : 0.f;
  float s  = wredsum(u*u);
  float un = fmaxf(sqrtf(s), MINN);
  float sc = sinhf(un)/un;
  float e  = sc*u;
  float s2 = wredsum(e*e);
  float r0 = sqrtf(fmaxf(1.f+s2, EPSF));
  float ubt   = lane ? ub[lane] : 0.f;
  float yn    = fmaxf(sqrtf(s2), MINN);
  float yhat  = e/yn;
  float alpha = wredsum(yhat*ubt);
  float w     = ubt - alpha*(1.f - r0)*yhat;
  float ux    = wredsum(e*w);
  float v0    = ux / fmaxf(r0, EPSF);
  float md    = wredsum(w*w) - v0*v0;
  float normu = fminf(sqrtf(fmaxf(md, EPSF)), MAXN);
  float th2   = fmaxf(normu, MINN);
  float ch    = coshf(th2);
  float shq   = sinhf(th2)/th2;
  float ov    = ch*(lane ? e : r0) + shq*(lane ? w : v0);
  float ot    = lane ? ov : 0.f;
  float s3    = wredsum(ot*ot);
  float o0    = sqrtf(fmaxf(1.f+s3, EPSF));
  float yn2 = fmaxf(sqrtf(s3), MINN);
  float th3 = fmaxf(o0, 1.f+EPSF);
  float gv  = lane ? acoshf(th3)*ot/yn2 : 0.f;
  g[(size_t)row*64 + lane] = gv;
}

// ---- transpose + bf16 convert: g[N][64] f32 -> gT[64][N] bf16
__global__ __launch_bounds__(256) void k_tr(const float* __restrict__ g,
                                            short* __restrict__ gT){
  __shared__ float t[64][65];
  int tid = threadIdx.x;
  int b   = blockIdx.x;
  int r   = tid >> 2;
  int c0  = (tid & 3)*16;
  const float* src = g + ((size_t)b*64 + r)*64 + c0;
  #pragma unroll
  for(int i = 0; i < 4; i++){
    float4 v = *(const float4*)(src + i*4);
    t[r][c0 + i*4 + 0] = v.x; t[r][c0 + i*4 + 1] = v.y;
    t[r][c0 + i*4 + 2] = v.z; t[r][c0 + i*4 + 3] = v.w;
  }
  __syncthreads();
  int n   = tid >> 2;
  int seg = tid & 3;
  short8 p0, p1;
  #pragma unroll
  for(int j = 0; j < 8; j++) p0[j] = (short)f2bf(t[seg*16 + j][n]);
  #pragma unroll
  for(int j = 0; j < 8; j++) p1[j] = (short)f2bf(t[seg*16 + 8 + j][n]);
  short* dst = gT + (size_t)n*KDIM + b*64 + seg*16;
  *(short8*)(dst)     = p0;
  *(short8*)(dst + 8) = p1;
}

// ---- full-K MFMA matmul, double-buffered LDS, ONE barrier per step, no split-K:
// agg[row][n] = adj[row,:] @ g[:,n] ; prsum[row] = sum(adj[row,:]) if FIRST
template<bool FIRST>
__global__ __launch_bounds__(512) void k_matmul(const float* __restrict__ adj,
                                                const short* __restrict__ gT,
                                                float* __restrict__ agg,
                                                float* __restrict__ prsum){
  __shared__ __align__(16) char lds[2*ABUF + 2*BBUF];   // ~25 KB
  char* Abase = lds;                 // two A buffers of ABUF
  char* Bbase = lds + 2*ABUF;        // two B buffers of BBUF
  int tid  = threadIdx.x;
  int lane = tid & 63, w = tid >> 6;
  int row0 = blockIdx.x * BM;

  // A staging: thread -> (row r, k-quad kq); coalesced float4, full 128B rows per 16 lanes
  int r  = tid >> 4;                 // 0..31
  int kq = tid & 15;                 // 16 quads = 64 k
  const float* ap = adj + (size_t)(row0 + r)*KDIM + kq*4;
  int AwOff = (kq >> 1)*APG + r*16 + (kq & 1)*8;

  // B staging: thread -> (col nB, k-octet q2); contiguous short8 from gT row
  int nB = tid & 63;
  int q2 = tid >> 6;                 // 0..7
  const short* bp = gT + (size_t)nB*KDIM + q2*8;
  int BwOff = q2*BPG + nB*16;

  // fragment roles: wave (wm,wn) computes rows wm*16..+16, cols wn*16..+16
  int wm = w >> 2, wn = w & 3;
  int fr = lane & 15, fk = lane >> 4;
  int ArdOff = fk*APG + (wm*16 + fr)*16;    // MFMA j=1 adds 4*APG
  int BrdOff = fk*BPG + (wn*16 + fr)*16;    // MFMA j=1 adds 4*BPG

  f32x4 acc = {0.f,0.f,0.f,0.f};
  float rs = 0.f;

  // prologue: stage step 0, preload step 1
  float4 a0 = *(const float4*)(ap);
  short8 b0 = *(const short8*)(bp);
  if (FIRST) rs += a0.x + a0.y + a0.z + a0.w;
  u16x4 ak0 = { f2bf(a0.x), f2bf(a0.y), f2bf(a0.z), f2bf(a0.w) };
  *(u16x4*)(Abase + AwOff) = ak0;
  *(short8*)(Bbase + BwOff) = b0;
  float4 aR = *(const float4*)(ap + BK2);
  short8 bR = *(const short8*)(bp + BK2);
  if (FIRST) rs += aR.x + aR.y + aR.z + aR.w;
  __syncthreads();

  for (int i = 0; i < NSTEP2; i++){
    const char* Ab = Abase + (i & 1)*ABUF;
    const char* Bb = Bbase + (i & 1)*BBUF;
    short8 af0 = *(const short8*)(Ab + ArdOff);
    short8 af1 = *(const short8*)(Ab + ArdOff + 4*APG);
    short8 bf0 = *(const short8*)(Bb + BrdOff);
    short8 bf1 = *(const short8*)(Bb + BrdOff + 4*BPG);
    float4 aN; short8 bN;
    if (i + 2 < NSTEP2){
      aN = *(const float4*)(ap + (size_t)(i+2)*BK2);
      bN = *(const short8*)(bp + (size_t)(i+2)*BK2);
      if (FIRST) rs += aN.x + aN.y + aN.z + aN.w;
    }
    acc = __builtin_amdgcn_mfma_f32_16x16x32_bf16(af0, bf0, acc, 0, 0, 0);
    acc = __builtin_amdgcn_mfma_f32_16x16x32_bf16(af1, bf1, acc, 0, 0, 0);
    if (i + 1 < NSTEP2){
      char* Aw = Abase + ((i+1) & 1)*ABUF;
      char* Bw = Bbase + ((i+1) & 1)*BBUF;
      u16x4 ak = { f2bf(aR.x), f2bf(aR.y), f2bf(aR.z), f2bf(aR.w) };
      *(u16x4*)(Aw + AwOff) = ak;
      *(short8*)(Bw + BwOff) = bR;
      aR = aN; bR = bN;
    }
    __syncthreads();
  }

  if (FIRST){
    rs += __shfl_xor(rs, 1);
    rs += __shfl_xor(rs, 2);
    rs += __shfl_xor(rs, 4);
    rs += __shfl_xor(rs, 8);
    if ((lane & 15) == 0) prsum[row0 + r] = rs;   // r = w*4 + (lane>>4)
  }
  // C write: D layout n = lane&15, m = (lane>>4)*4 + q
  float* ob = agg + (size_t)(row0 + wm*16)*64 + wn*16;
  #pragma unroll
  for(int q = 0; q < 4; q++){
    ob[(size_t)((lane >> 4)*4 + q)*64 + (lane & 15)] = acc[q];
  }
}

// ---- fused: (layer1: rinv compute/store) + postagg chain -> h
template<int LAYER>
__global__ __launch_bounds__(256) void k_post(const float* __restrict__ agg,
                                              const float* __restrict__ prsum,
                                              float* __restrict__ rinv,
                                              float* __restrict__ h){
  int tid = threadIdx.x; int lane = tid & 63;
  int row = blockIdx.x*4 + (tid >> 6);
  float s = agg[(size_t)row*64 + lane];
  float ri;
  if (LAYER == 1){
    float rsum = prsum[row];
    ri = (rsum != 0.f) ? 1.f/rsum : 0.f;
    if (lane == 0) rinv[row] = ri;
  } else {
    ri = rinv[row];
  }
  float a  = s * ri;
  float at = lane ? a : 0.f;
  float ss = wredsum(at*at);
  float un = fmaxf(sqrtf(ss), MINN);
  float sc = sinhf(un)/un;
  float e  = sc*at;
  float s2 = wredsum(e*e);
  float x0 = sqrtf(fmaxf(1.f+s2, EPSF));
  float yn = fmaxf(sqrtf(s2), MINN);
  float th = fmaxf(x0, 1.f+EPSF);
  float lt = lane ? acoshf(th)*e/yn : 0.f;
  float rl = fmaxf(lt, 0.f);
  float s3 = wredsum(rl*rl);
  float rn = fmaxf(sqrtf(s3), MINN);
  float sc2= sinhf(rn)/rn;
  float e2 = sc2*rl;
  float s4 = wredsum(e2*e2);
  float h0 = sqrtf(fmaxf(1.f+s4, EPSF));
  h[(size_t)row*64 + lane] = lane ? e2 : h0;
}

extern "C" void kernel_launch(void* const* d_in, const int* in_sizes, int n_in,
                              void* d_out, int out_size, void* d_ws, size_t ws_size,
                              hipStream_t stream){
  const float* x   = (const float*)d_in[0];
  const float* adj = (const float*)d_in[1];
  const float* W1  = (const float*)d_in[2];
  const float* b1  = (const float*)d_in[3];
  const float* W2  = (const float*)d_in[4];
  const float* b2  = (const float*)d_in[5];
  float* out = (float*)d_out;
  float* h1  = out;
  float* h2  = out + (size_t)NROWS*64;

  float* wsf   = (float*)d_ws;
  float* gbuf  = wsf;                              // N*64 f32
  float* aggb  = gbuf  + (size_t)NROWS*64;         // N*64 f32
  float* prsum = aggb  + (size_t)NROWS*64;         // N
  float* rinv  = prsum + NROWS;                    // N
  float* ubs   = rinv  + NROWS;                    // 128
  short* gT    = (short*)(ubs + 128);              // 64*N bf16

  k_bias<<<1, 128, 0, stream>>>(b1, b2, ubs);
  // layer 1
  k_linear<0><<<NROWS/4, 256, 0, stream>>>(x, W1, ubs, gbuf);
  k_tr<<<NROWS/64, 256, 0, stream>>>(gbuf, gT);
  k_matmul<true><<<NROWS/BM, 512, 0, stream>>>(adj, gT, aggb, prsum);
  k_post<1><<<NROWS/4, 256, 0, stream>>>(aggb, prsum, rinv, h1);
  // layer 2
  k_linear<1><<<NROWS/4, 256, 0, stream>>>(h1, W2, ubs + 64, gbuf);
  k_tr<<<NROWS/64, 256, 0, stream>>>(gbuf, gT);
  k_matmul<false><<<NROWS/BM, 512, 0, stream>>>(adj, gT, aggb, prsum);
  k_post<2><<<NROWS/4, 256, 0, stream>>>(aggb, prsum, rinv, h2);
}